// Round 20
// baseline (87.707 us; speedup 1.0000x reference)
//
#include <hip/hip_runtime.h>
#include <hip/hip_bf16.h>

typedef __hip_bfloat16 bf16;

// ---------- constants ----------
// B=2, N=2048, C=128, H=8, hd=16, branches=3, hid=768
// I/O fp32; intermediates bf16 except xc (fp32 residual). Weights pre-transposed
// to bf16 Wt[N][K] (k_wt). Q pre-scaled by 0.25*log2e (exp2-domain softmax).
// V stored tiled-transposed [bh][kb][d16][key64]. Attention: barrier-free, LDS-free,
// split-K (2x1024), 2 Q-tiles/wave, shared negm/m guarded rescale (R18-exact).
// LN1 fused into k_qkv_m staging; LN2 fused into k_fc1_m staging (identical math:
// fp32 LN then bf16 convert at the same point; only sum order differs).
// Split-K merge fused into k_proj_m. 6 launches total.

static __device__ __forceinline__ float b2f(bf16 h) { return __bfloat162float(h); }
static __device__ __forceinline__ bf16 f2b(float f) { return __float2bfloat16(f); }
static __device__ __forceinline__ unsigned short f2bu(float f) {
    bf16 h = f2b(f);
    return *reinterpret_cast<unsigned short*>(&h);
}
static __device__ __forceinline__ float bs2f(short s) {
    return __uint_as_float(((unsigned)(unsigned short)s) << 16);
}

typedef __attribute__((ext_vector_type(8))) short short8;
typedef __attribute__((ext_vector_type(4))) short short4v;
typedef __attribute__((ext_vector_type(16))) float f32x16;
typedef __attribute__((ext_vector_type(2))) int int2v;

#define QSCALE 0.36067376022224085f  // 0.25 * log2(e)

// ================= K0: weight transposes+convert only =================
__global__ __launch_bounds__(256) void k_wt(const float* __restrict__ qkv_w, const float* __restrict__ proj_w,
                                            const float* __restrict__ fc1_w, const float* __restrict__ fc2_w,
                                            bf16* __restrict__ wtq, bf16* __restrict__ wtp,
                                            bf16* __restrict__ wt1, bf16* __restrict__ wt2) {
    int idx = blockIdx.x * 256 + threadIdx.x;   // < 786432
    if (idx < 147456) {
        int bq = idx / 49152, i2 = idx % 49152;
        int n = i2 >> 7, k = i2 & 127;
        wtq[idx] = f2b(qkv_w[bq * 49152 + k * 384 + n]);
    } else if (idx < 196608) {
        int j = idx - 147456;
        int bq = j / 16384, i2 = j % 16384;
        int n = i2 >> 7, k = i2 & 127;
        wtp[j] = f2b(proj_w[bq * 16384 + k * 128 + n]);
    } else if (idx < 491520) {
        int j = idx - 196608;
        int n = j / 384, k = j - n * 384;
        wt1[j] = f2b(fc1_w[k * 768 + n]);
    } else {
        int j = idx - 491520;
        int n = j / 768, k = j - n * 768;
        wt2[j] = f2b(fc2_w[k * 384 + n]);
    }
}

// ================= shared MFMA GEMM tile: C64x64 = A[M,K] . Wt[N,K]^T =================
__device__ __forceinline__ f32x16 gemm_tile(const short* __restrict__ A, const short* __restrict__ W,
                                            int K, int rowbase, int colbase,
                                            short* als, short* wls) {
    int tid = threadIdx.x;
    int wid = tid >> 6, lane = tid & 63;
    int hi = lane >> 5, l31 = lane & 31;
    int wm = wid >> 1, wn = wid & 1;
    int sr = tid >> 3, skb = tid & 7;   // staging: row (0..31), k-block (0..7)
    f32x16 acc;
#pragma unroll
    for (int i = 0; i < 16; ++i) acc[i] = 0.f;
    for (int k0 = 0; k0 < K; k0 += 64) {
        __syncthreads();
#pragma unroll
        for (int pass = 0; pass < 2; ++pass) {
            int r = sr + pass * 32;
            short8 av = *(const short8*)&A[(size_t)(rowbase + r) * K + k0 + skb * 8];
            *(short8*)&als[r * 64 + ((skb ^ (r & 7)) * 8)] = av;
            short8 wv = *(const short8*)&W[(size_t)(colbase + r) * K + k0 + skb * 8];
            *(short8*)&wls[r * 64 + ((skb ^ (r & 7)) * 8)] = wv;
        }
        __syncthreads();
#pragma unroll
        for (int ks = 0; ks < 4; ++ks) {
            int ra = wm * 32 + l31;
            int rb = wn * 32 + l31;
            int kb = ks * 2 + hi;
            short8 af = *(const short8*)&als[ra * 64 + ((kb ^ (ra & 7)) * 8)];
            short8 bf = *(const short8*)&wls[rb * 64 + ((kb ^ (rb & 7)) * 8)];
            acc = __builtin_amdgcn_mfma_f32_32x32x16_bf16(af, bf, acc, 0, 0, 0);
        }
    }
    return acc;
}

// ================= K2: QKV GEMM (64x128 tile) with FUSED LN1 in A-staging =================
// grid (64, 3, 3): blockIdx.y selects the 128-col slab = exactly one of {q,k,v}.
__global__ __launch_bounds__(256) void k_qkv_m(const float* __restrict__ x1, const float* __restrict__ x2,
                                               const float* __restrict__ x3, const float* __restrict__ g,
                                               const float* __restrict__ bvec, const bf16* __restrict__ wt,
                                               bf16* __restrict__ q, bf16* __restrict__ k, bf16* __restrict__ v) {
    __shared__ short als[64 * 64];     // 8 KB
    __shared__ short wls[128 * 64];    // 16 KB
    __shared__ float part[64][4][2];   // 2 KB
    __shared__ float rowstat[64][2];   // 0.5 KB
    int branch = blockIdx.z;
    const float* X = (branch == 0) ? x1 : (branch == 1 ? x2 : x3);
    const short* W = (const short*)wt + (size_t)branch * 384 * 128;
    int rowbase = blockIdx.x * 64, colbase = blockIdx.y * 128;
    int tid = threadIdx.x;
    // per-row LN1 stats over 128 cols (4 segs of 32)
    {
        int rr = tid >> 2, seg = tid & 3;
        const float* xr = X + (size_t)(rowbase + rr) * 128 + seg * 32;
        float s = 0.f, sq = 0.f;
#pragma unroll
        for (int j = 0; j < 32; j += 4) {
            float4 v4 = *(const float4*)&xr[j];
            s += (v4.x + v4.y) + (v4.z + v4.w);
            sq += (v4.x * v4.x + v4.y * v4.y) + (v4.z * v4.z + v4.w * v4.w);
        }
        part[rr][seg][0] = s; part[rr][seg][1] = sq;
    }
    __syncthreads();
    if ((tid & 3) == 0) {
        int rr = tid >> 2;
        float ts = (part[rr][0][0] + part[rr][1][0]) + (part[rr][2][0] + part[rr][3][0]);
        float tq = (part[rr][0][1] + part[rr][1][1]) + (part[rr][2][1] + part[rr][3][1]);
        float mean = ts * (1.f / 128.f);
        float var = tq * (1.f / 128.f) - mean * mean;
        rowstat[rr][0] = mean; rowstat[rr][1] = rsqrtf(var + 1e-5f);
    }
    // gemm (64x128 tile, 2 accs); A staged with inline LN
    int wid = tid >> 6, lane = tid & 63;
    int hi = lane >> 5, l31 = lane & 31;
    int wm = wid >> 1, wn = wid & 1;
    int sr = tid >> 3, skb = tid & 7;
    const float* gb = g + branch * 128;
    const float* bb2 = bvec + branch * 128;
    f32x16 acc0, acc1;
#pragma unroll
    for (int i = 0; i < 16; ++i) { acc0[i] = 0.f; acc1[i] = 0.f; }
    for (int k0 = 0; k0 < 128; k0 += 64) {
        __syncthreads();
#pragma unroll
        for (int pass = 0; pass < 2; ++pass) {
            int r = sr + pass * 32;
            float mean = rowstat[r][0], rstd = rowstat[r][1];
            const float* xr = X + (size_t)(rowbase + r) * 128 + k0 + skb * 8;
            short8 av;
#pragma unroll
            for (int j = 0; j < 8; ++j) {
                int c = k0 + skb * 8 + j;
                av[j] = (short)f2bu((xr[j] - mean) * rstd * gb[c] + bb2[c]);
            }
            *(short8*)&als[r * 64 + ((skb ^ (r & 7)) * 8)] = av;
        }
#pragma unroll
        for (int pass = 0; pass < 4; ++pass) {
            int r = sr + pass * 32;
            short8 wv = *(const short8*)&W[(size_t)(colbase + r) * 128 + k0 + skb * 8];
            *(short8*)&wls[r * 64 + ((skb ^ (r & 7)) * 8)] = wv;
        }
        __syncthreads();
#pragma unroll
        for (int ks = 0; ks < 4; ++ks) {
            int ra = wm * 32 + l31;
            int rb0 = wn * 64 + l31;
            int rb1 = wn * 64 + 32 + l31;
            int kb = ks * 2 + hi;
            short8 af = *(const short8*)&als[ra * 64 + ((kb ^ (ra & 7)) * 8)];
            short8 bf0 = *(const short8*)&wls[rb0 * 64 + ((kb ^ (rb0 & 7)) * 8)];
            short8 bf1 = *(const short8*)&wls[rb1 * 64 + ((kb ^ (rb1 & 7)) * 8)];
            acc0 = __builtin_amdgcn_mfma_f32_32x32x16_bf16(af, bf0, acc0, 0, 0, 0);
            acc1 = __builtin_amdgcn_mfma_f32_32x32x16_bf16(af, bf1, acc1, 0, 0, 0);
        }
    }
    int which = blockIdx.y;                 // 0=q, 1=k, 2=v (block-uniform)
    int c0 = wn * 64 + l31;                 // 0..127 within slab
    int c1 = c0 + 32;
    if (which < 2) {
        bf16* dst = (which == 0) ? q : k;
        float scl = (which == 0) ? QSCALE : 1.0f;
        int h0 = c0 >> 4, d0 = c0 & 15;
        int h1 = c1 >> 4, d1 = c1 & 15;
#pragma unroll
        for (int i = 0; i < 16; ++i) {
            int mrow = (i & 3) + 8 * (i >> 2) + 4 * hi;
            int token = rowbase + wm * 32 + mrow;
            int bb = token >> 11, n = token & 2047;
            size_t rowb = (((size_t)branch * 2 + bb) * 8);
            dst[((rowb + h0) * 2048 + n) * 16 + d0] = f2b(acc0[i] * scl);
            dst[((rowb + h1) * 2048 + n) * 16 + d1] = f2b(acc1[i] * scl);
        }
    } else {
        int h0 = c0 >> 4, d0 = c0 & 15;
        int h1 = c1 >> 4, d1 = c1 & 15;
#pragma unroll
        for (int i = 0; i < 16; ++i) {
            int mrow = (i & 3) + 8 * (i >> 2) + 4 * hi;
            int token = rowbase + wm * 32 + mrow;
            int bb = token >> 11, n = token & 2047;
            size_t bhb = ((size_t)(branch * 2 + bb) * 8);
            v[(((bhb + h0) * 32 + (n >> 6)) * 16 + d0) * 64 + (n & 63)] = f2b(acc0[i]);
            v[(((bhb + h1) * 32 + (n >> 6)) * 16 + d1) * 64 + (n & 63)] = f2b(acc1[i]);
        }
    }
}

// ---- one attention stream: QK (C=-m) -> exp2 -> cvt_pk -> permlane -> 4 PV into acc ----
static __device__ __forceinline__ void attn_stream(short8 kf0, short8 kf1,
                                                   short8 vf1, short8 vf2, short8 vf3, short8 vf4,
                                                   short8 qf, const f32x16& negm, f32x16& acc) {
    f32x16 pa = __builtin_amdgcn_mfma_f32_32x32x16_bf16(kf0, qf, negm, 0, 0, 0);
    f32x16 pb = __builtin_amdgcn_mfma_f32_32x32x16_bf16(kf1, qf, negm, 0, 0, 0);
#pragma unroll
    for (int r = 0; r < 16; ++r) pa[r] = __builtin_amdgcn_exp2f(pa[r]);
#pragma unroll
    for (int r = 0; r < 16; ++r) pb[r] = __builtin_amdgcn_exp2f(pb[r]);
    unsigned wa[8], wb[8];
#pragma unroll
    for (int e = 0; e < 8; ++e) {
        unsigned t;
        asm("v_cvt_pk_bf16_f32 %0, %1, %2" : "=v"(t) : "v"(pa[2 * e]), "v"(pa[2 * e + 1]));
        wa[e] = t;
        asm("v_cvt_pk_bf16_f32 %0, %1, %2" : "=v"(t) : "v"(pb[2 * e]), "v"(pb[2 * e + 1]));
        wb[e] = t;
    }
    union { unsigned u[4]; short8 v; } b1, b2, b3, b4;
    {
        auto r0 = __builtin_amdgcn_permlane32_swap((int)wa[0], (int)wa[2], false, false);
        b1.u[0] = (unsigned)r0[0]; b1.u[2] = (unsigned)r0[1];
        auto r1 = __builtin_amdgcn_permlane32_swap((int)wa[1], (int)wa[3], false, false);
        b1.u[1] = (unsigned)r1[0]; b1.u[3] = (unsigned)r1[1];
        auto r2 = __builtin_amdgcn_permlane32_swap((int)wa[4], (int)wa[6], false, false);
        b2.u[0] = (unsigned)r2[0]; b2.u[2] = (unsigned)r2[1];
        auto r3 = __builtin_amdgcn_permlane32_swap((int)wa[5], (int)wa[7], false, false);
        b2.u[1] = (unsigned)r3[0]; b2.u[3] = (unsigned)r3[1];
        auto r4 = __builtin_amdgcn_permlane32_swap((int)wb[0], (int)wb[2], false, false);
        b3.u[0] = (unsigned)r4[0]; b3.u[2] = (unsigned)r4[1];
        auto r5 = __builtin_amdgcn_permlane32_swap((int)wb[1], (int)wb[3], false, false);
        b3.u[1] = (unsigned)r5[0]; b3.u[3] = (unsigned)r5[1];
        auto r6 = __builtin_amdgcn_permlane32_swap((int)wb[4], (int)wb[6], false, false);
        b4.u[0] = (unsigned)r6[0]; b4.u[2] = (unsigned)r6[1];
        auto r7 = __builtin_amdgcn_permlane32_swap((int)wb[5], (int)wb[7], false, false);
        b4.u[1] = (unsigned)r7[0]; b4.u[3] = (unsigned)r7[1];
    }
    acc = __builtin_amdgcn_mfma_f32_32x32x16_bf16(vf1, b1.v, acc, 0, 0, 0);
    acc = __builtin_amdgcn_mfma_f32_32x32x16_bf16(vf2, b2.v, acc, 0, 0, 0);
    acc = __builtin_amdgcn_mfma_f32_32x32x16_bf16(vf3, b3.v, acc, 0, 0, 0);
    acc = __builtin_amdgcn_mfma_f32_32x32x16_bf16(vf4, b4.v, acc, 0, 0, 0);
}

// ================= K3: MFMA attention — R18-exact =================
__global__ __launch_bounds__(128, 3) void k_attn(const bf16* __restrict__ qg, const bf16* __restrict__ kg,
                                                 const bf16* __restrict__ vg, bf16* __restrict__ pacc,
                                                 float2* __restrict__ psm) {
    int bh = blockIdx.x;            // (branch*2+b)*8+h
    int qblk = blockIdx.y;          // 0..15 (tile B = qblk+16)
    int split = blockIdx.z;         // 0..1
    size_t base = (size_t)bh * (2048 * 16);
    size_t vtbase = (size_t)bh * 32768;   // tiled V^T base (32 tiles x 1024)
    int tid = threadIdx.x, wave = tid >> 6, lane = tid & 63;
    int hi = lane >> 5, l31 = lane & 31;
    int qrowA = qblk * 64 + wave * 32 + l31;
    int qrowB = (qblk + 16) * 64 + wave * 32 + l31;
    const short* qs = (const short*)qg;
    const short* ks = (const short*)kg;
    const short* vts = (const short*)vg;
    short8 qfA = *(const short8*)&qs[base + (size_t)qrowA * 16 + hi * 8];
    short8 qfB = *(const short8*)&qs[base + (size_t)qrowB * 16 + hi * 8];

    short8 one8;
#pragma unroll
    for (int j = 0; j < 8; ++j) one8[j] = (short)0x3F80;   // bf16 1.0

    f32x16 accA, accB, negm;
#pragma unroll
    for (int r = 0; r < 16; ++r) { accA[r] = 0.f; accB[r] = 0.f; negm[r] = -16.f; }
    float m = 16.f;

    int kbeg = split * 1024, kend = kbeg + 1024;

    for (int c0 = kbeg; c0 < kend; c0 += 64) {
        float mx = fmaxf(accA[8], accB[8]);
        if (__any(mx > 2.68435456e8f)) {   // 2^28
            int e = (__float_as_int(mx) >> 23) - 127;
            int shift = e > 16 ? e - 16 : 0;
            float fac = __int_as_float((127 - shift) << 23);   // 2^-shift
            m += (float)shift;
#pragma unroll
            for (int r = 0; r < 16; ++r) negm[r] = -m;
#pragma unroll
            for (int r = 0; r < 16; ++r) { accA[r] *= fac; accB[r] *= fac; }
        }
        short8 kf0 = *(const short8*)&ks[base + (size_t)(c0 + l31) * 16 + hi * 8];
        short8 kf1 = *(const short8*)&ks[base + (size_t)(c0 + 32 + l31) * 16 + hi * 8];
        short8 vf1 = one8, vf2 = one8, vf3 = one8, vf4 = one8;
        if (l31 < 16) {
            const short* vt = &vts[vtbase + (size_t)(c0 >> 6) * 1024 + l31 * 64 + hi * 8];
            vf1 = *(const short8*)&vt[0];
            vf2 = *(const short8*)&vt[16];
            vf3 = *(const short8*)&vt[32];
            vf4 = *(const short8*)&vt[48];
        }
        attn_stream(kf0, kf1, vf1, vf2, vf3, vf4, qfA, negm, accA);
        attn_stream(kf0, kf1, vf1, vf2, vf3, vf4, qfB, negm, accB);
    }
    short* pp = (short*)pacc;
    {
        size_t pidx = ((size_t)(split * 48 + bh) * 2048 + qrowA) * 16;
        unsigned u0 = (unsigned)f2bu(accA[0]) | ((unsigned)f2bu(accA[1]) << 16);
        unsigned u1 = (unsigned)f2bu(accA[2]) | ((unsigned)f2bu(accA[3]) << 16);
        unsigned u2 = (unsigned)f2bu(accA[4]) | ((unsigned)f2bu(accA[5]) << 16);
        unsigned u3 = (unsigned)f2bu(accA[6]) | ((unsigned)f2bu(accA[7]) << 16);
        int2v w01; w01.x = (int)u0; w01.y = (int)u1;
        int2v w23; w23.x = (int)u2; w23.y = (int)u3;
        *(int2v*)&pp[pidx + 4 * hi] = w01;
        *(int2v*)&pp[pidx + 8 + 4 * hi] = w23;
        if (hi == 0) {
            float2 sm; sm.x = accA[8]; sm.y = m;
            psm[(size_t)(split * 48 + bh) * 2048 + qrowA] = sm;
        }
    }
    {
        size_t pidx = ((size_t)(split * 48 + bh) * 2048 + qrowB) * 16;
        unsigned u0 = (unsigned)f2bu(accB[0]) | ((unsigned)f2bu(accB[1]) << 16);
        unsigned u1 = (unsigned)f2bu(accB[2]) | ((unsigned)f2bu(accB[3]) << 16);
        unsigned u2 = (unsigned)f2bu(accB[4]) | ((unsigned)f2bu(accB[5]) << 16);
        unsigned u3 = (unsigned)f2bu(accB[6]) | ((unsigned)f2bu(accB[7]) << 16);
        int2v w01; w01.x = (int)u0; w01.y = (int)u1;
        int2v w23; w23.x = (int)u2; w23.y = (int)u3;
        *(int2v*)&pp[pidx + 4 * hi] = w01;
        *(int2v*)&pp[pidx + 8 + 4 * hi] = w23;
        if (hi == 0) {
            float2 sm; sm.x = accB[8]; sm.y = m;
            psm[(size_t)(split * 48 + bh) * 2048 + qrowB] = sm;
        }
    }
}

// ================= K4: proj GEMM with FUSED split-K merge in A-staging =================
__global__ __launch_bounds__(256) void k_proj_m(const bf16* __restrict__ pacc, const float2* __restrict__ psm,
                                                const bf16* __restrict__ wt, const float* __restrict__ pb,
                                                const float* __restrict__ x1, const float* __restrict__ x2,
                                                const float* __restrict__ x3, float* __restrict__ xc) {
    __shared__ short als[64 * 64];
    __shared__ short wls[64 * 64];
    int branch = blockIdx.z;
    const short* W = (const short*)wt + (size_t)branch * 128 * 128;
    const short* pp = (const short*)pacc;
    int rowbase = blockIdx.x * 64, colbase = blockIdx.y * 64;
    int tid = threadIdx.x;
    int wid = tid >> 6, lane = tid & 63;
    int hi = lane >> 5, l31 = lane & 31;
    int wm = wid >> 1, wn = wid & 1;
    int sr = tid >> 3, skb = tid & 7;
    f32x16 acc;
#pragma unroll
    for (int i = 0; i < 16; ++i) acc[i] = 0.f;
    for (int k0 = 0; k0 < 128; k0 += 64) {
        __syncthreads();
#pragma unroll
        for (int pass = 0; pass < 2; ++pass) {
            int r = sr + pass * 32;
            int row = rowbase + r;                  // token row within branch
            int bb = row >> 11, n = row & 2047;
            int h = (k0 >> 4) + (skb >> 1);         // head for these 8 cols
            int dlo = (skb & 1) * 8;                // d offset (0 or 8)
            size_t bh = (size_t)(branch * 2 + bb) * 8 + h;
            size_t ridx = bh * 2048 + n;
            float2 sm0 = psm[ridx];
            float2 sm1 = psm[(size_t)48 * 2048 + ridx];
            float mp = fmaxf(sm0.y, sm1.y);
            float w0 = __builtin_amdgcn_exp2f(sm0.y - mp);
            float w1 = __builtin_amdgcn_exp2f(sm1.y - mp);
            float inv = 1.f / (sm0.x * w0 + sm1.x * w1);
            w0 *= inv; w1 *= inv;
            short8 a0 = *(const short8*)&pp[ridx * 16 + dlo];
            short8 a1 = *(const short8*)&pp[((size_t)48 * 2048 + ridx) * 16 + dlo];
            short8 av;
#pragma unroll
            for (int j = 0; j < 8; ++j)
                av[j] = (short)f2bu(bs2f(a0[j]) * w0 + bs2f(a1[j]) * w1);
            *(short8*)&als[r * 64 + ((skb ^ (r & 7)) * 8)] = av;
            short8 wv = *(const short8*)&W[(size_t)(colbase + r) * 128 + k0 + skb * 8];
            *(short8*)&wls[r * 64 + ((skb ^ (r & 7)) * 8)] = wv;
        }
        __syncthreads();
#pragma unroll
        for (int ks = 0; ks < 4; ++ks) {
            int ra = wm * 32 + l31;
            int rb = wn * 32 + l31;
            int kb = ks * 2 + hi;
            short8 af = *(const short8*)&als[ra * 64 + ((kb ^ (ra & 7)) * 8)];
            short8 bf = *(const short8*)&wls[rb * 64 + ((kb ^ (rb & 7)) * 8)];
            acc = __builtin_amdgcn_mfma_f32_32x32x16_bf16(af, bf, acc, 0, 0, 0);
        }
    }
    int c = colbase + wn * 32 + l31;        // 0..127
    float bias = pb[branch * 128 + c];
    const float* xp = (branch == 0) ? x1 : (branch == 1 ? x2 : x3);
#pragma unroll
    for (int i = 0; i < 16; ++i) {
        int mrow = (i & 3) + 8 * (i >> 2) + 4 * hi;
        int row = rowbase + wm * 32 + mrow;
        xc[(size_t)row * 384 + branch * 128 + c] = acc[i] + bias + xp[(size_t)row * 128 + c];
    }
}

// ================= K6: FC1 GEMM (64x128 tile) with FUSED LN2 in A-staging + GELU =================
__global__ __launch_bounds__(256) void k_fc1_m(const float* __restrict__ xc, const float* __restrict__ g,
                                               const float* __restrict__ bvec, const bf16* __restrict__ wt,
                                               const float* __restrict__ bias, bf16* __restrict__ h) {
    __shared__ short als[64 * 64];     // 8 KB
    __shared__ short wls[128 * 64];    // 16 KB
    __shared__ float part[64][4][2];   // 2 KB
    __shared__ float rowstat[64][2];   // 0.5 KB
    const short* W = (const short*)wt;
    int rowbase = blockIdx.x * 64, colbase = blockIdx.y * 128;
    int tid = threadIdx.x;
    // per-row LN2 stats over 384 cols (4 segs of 96)
    {
        int rr = tid >> 2, seg = tid & 3;
        const float* xr = xc + (size_t)(rowbase + rr) * 384 + seg * 96;
        float s = 0.f, sq = 0.f;
#pragma unroll
        for (int j = 0; j < 96; j += 4) {
            float4 v4 = *(const float4*)&xr[j];
            s += (v4.x + v4.y) + (v4.z + v4.w);
            sq += (v4.x * v4.x + v4.y * v4.y) + (v4.z * v4.z + v4.w * v4.w);
        }
        part[rr][seg][0] = s; part[rr][seg][1] = sq;
    }
    __syncthreads();
    if ((tid & 3) == 0) {
        int rr = tid >> 2;
        float ts = (part[rr][0][0] + part[rr][1][0]) + (part[rr][2][0] + part[rr][3][0]);
        float tq = (part[rr][0][1] + part[rr][1][1]) + (part[rr][2][1] + part[rr][3][1]);
        float mean = ts * (1.f / 384.f);
        float var = tq * (1.f / 384.f) - mean * mean;
        rowstat[rr][0] = mean; rowstat[rr][1] = rsqrtf(var + 1e-5f);
    }
    int wid = tid >> 6, lane = tid & 63;
    int hi = lane >> 5, l31 = lane & 31;
    int wm = wid >> 1, wn = wid & 1;
    int sr = tid >> 3, skb = tid & 7;
    f32x16 acc0, acc1;
#pragma unroll
    for (int i = 0; i < 16; ++i) { acc0[i] = 0.f; acc1[i] = 0.f; }
    for (int k0 = 0; k0 < 384; k0 += 64) {
        __syncthreads();
#pragma unroll
        for (int pass = 0; pass < 2; ++pass) {
            int r = sr + pass * 32;
            float mean = rowstat[r][0], rstd = rowstat[r][1];
            const float* xr = xc + (size_t)(rowbase + r) * 384 + k0 + skb * 8;
            short8 av;
#pragma unroll
            for (int j = 0; j < 8; ++j) {
                int c = k0 + skb * 8 + j;
                av[j] = (short)f2bu((xr[j] - mean) * rstd * g[c] + bvec[c]);
            }
            *(short8*)&als[r * 64 + ((skb ^ (r & 7)) * 8)] = av;
        }
#pragma unroll
        for (int pass = 0; pass < 4; ++pass) {
            int r = sr + pass * 32;
            short8 wv = *(const short8*)&W[(size_t)(colbase + r) * 384 + k0 + skb * 8];
            *(short8*)&wls[r * 64 + ((skb ^ (r & 7)) * 8)] = wv;
        }
        __syncthreads();
#pragma unroll
        for (int ks = 0; ks < 4; ++ks) {
            int ra = wm * 32 + l31;
            int rb0 = wn * 64 + l31;
            int rb1 = wn * 64 + 32 + l31;
            int kb = ks * 2 + hi;
            short8 af = *(const short8*)&als[ra * 64 + ((kb ^ (ra & 7)) * 8)];
            short8 bf0 = *(const short8*)&wls[rb0 * 64 + ((kb ^ (rb0 & 7)) * 8)];
            short8 bf1 = *(const short8*)&wls[rb1 * 64 + ((kb ^ (rb1 & 7)) * 8)];
            acc0 = __builtin_amdgcn_mfma_f32_32x32x16_bf16(af, bf0, acc0, 0, 0, 0);
            acc1 = __builtin_amdgcn_mfma_f32_32x32x16_bf16(af, bf1, acc1, 0, 0, 0);
        }
    }
    int c0 = colbase + wn * 64 + l31;       // 0..767
    int c1 = c0 + 32;
    float bs0 = bias[c0];
    float bs1 = bias[c1];
#pragma unroll
    for (int i = 0; i < 16; ++i) {
        int mrow = (i & 3) + 8 * (i >> 2) + 4 * hi;
        int row = rowbase + wm * 32 + mrow;
        float v0 = acc0[i] + bs0;
        float v1 = acc1[i] + bs1;
        float g0 = 0.5f * v0 * (1.f + erff(v0 * 0.70710678118f));
        float g1 = 0.5f * v1 * (1.f + erff(v1 * 0.70710678118f));
        h[(size_t)row * 768 + c0] = f2b(g0);
        h[(size_t)row * 768 + c1] = f2b(g1);
    }
}

// ================= K7: FC2 GEMM (MFMA) + bias + residual -> split fp32 outputs =================
__global__ __launch_bounds__(256) void k_fc2_m(const bf16* __restrict__ h, const bf16* __restrict__ wt,
                                               const float* __restrict__ bias, const float* __restrict__ xc,
                                               float* __restrict__ outp) {
    __shared__ short als[64 * 64];
    __shared__ short wls[64 * 64];
    const short* A = (const short*)h;
    const short* W = (const short*)wt;
    int rowbase = blockIdx.x * 64, colbase = blockIdx.y * 64;
    f32x16 acc = gemm_tile(A, W, 768, rowbase, colbase, als, wls);
    int tid = threadIdx.x, wid = tid >> 6, lane = tid & 63;
    int hi = lane >> 5, l31 = lane & 31;
    int wm = wid >> 1, wn = wid & 1;
    int c = colbase + wn * 32 + l31;        // 0..383
    float bs = bias[c];
    int which = c >> 7, cc = c & 127;
#pragma unroll
    for (int i = 0; i < 16; ++i) {
        int mrow = (i & 3) + 8 * (i >> 2) + 4 * hi;
        int row = rowbase + wm * 32 + mrow;
        outp[(size_t)which * 524288 + (size_t)row * 128 + cc] = acc[i] + bs + xc[(size_t)row * 384 + c];
    }
}

// ================= launch =================
extern "C" void kernel_launch(void* const* d_in, const int* in_sizes, int n_in,
                              void* d_out, int out_size, void* d_ws, size_t ws_size,
                              hipStream_t stream) {
    const float* x1     = (const float*)d_in[0];
    const float* x2     = (const float*)d_in[1];
    const float* x3     = (const float*)d_in[2];
    const float* ln1_g  = (const float*)d_in[3];
    const float* ln1_b  = (const float*)d_in[4];
    const float* qkv_w  = (const float*)d_in[5];
    const float* proj_w = (const float*)d_in[6];
    const float* proj_b = (const float*)d_in[7];
    const float* ln2_g  = (const float*)d_in[8];
    const float* ln2_b  = (const float*)d_in[9];
    const float* fc1_w  = (const float*)d_in[10];
    const float* fc1_b  = (const float*)d_in[11];
    const float* fc2_w  = (const float*)d_in[12];
    const float* fc2_b  = (const float*)d_in[13];

    char* ws = (char*)d_ws;
    const size_t SB = 3145728;  // bf16 buffer of 1.5M elems
    bf16* qb  = (bf16*)(ws + 1 * SB);
    bf16* kb  = (bf16*)(ws + 2 * SB);
    bf16* vb  = (bf16*)(ws + 3 * SB);   // tiled V^T
    float* xc = (float*)(ws + 5 * SB);            // 4096*384*4 = 6291456 B
    bf16* hb  = (bf16*)(ws + 6 * SB + 6291456);   // 4096*768*2 = 6291456 B
    char* wbase = ws + 31457280;
    bf16* wtq = (bf16*)(wbase);                   // 3*384*128*2 = 294912
    bf16* wtp = (bf16*)(wbase + 294912);          // 3*128*128*2 = 98304
    bf16* wt1 = (bf16*)(wbase + 393216);          // 768*384*2   = 589824
    bf16* wt2 = (bf16*)(wbase + 983040);          // 384*768*2   = 589824
    // total = 33030144 B (~31.5 MB)
    // Split-K attention partials (written by k_attn, consumed by k_proj_m, then
    // their space is clobbered by hb in k_fc1_m — stream-ordered, safe):
    bf16*  pacc = (bf16*)(ws + 22020096);         // 2*48*2048*16*2 = 6291456 B
    float2* psm = (float2*)(ws + 28311552);       // 2*48*2048*8    = 1572864 B

    k_wt<<<3072, 256, 0, stream>>>(qkv_w, proj_w, fc1_w, fc2_w, wtq, wtp, wt1, wt2);
    k_qkv_m<<<dim3(64, 3, 3), 256, 0, stream>>>(x1, x2, x3, ln1_g, ln1_b, wtq, qb, kb, vb);
    k_attn<<<dim3(48, 16, 2), 128, 0, stream>>>(qb, kb, vb, pacc, psm);
    k_proj_m<<<dim3(64, 2, 3), 256, 0, stream>>>(pacc, psm, wtp, proj_b, x1, x2, x3, xc);
    k_fc1_m<<<dim3(64, 6, 1), 256, 0, stream>>>(xc, ln2_g, ln2_b, wt1, fc1_b, hb);
    k_fc2_m<<<dim3(64, 6, 1), 256, 0, stream>>>(hb, wt2, fc2_b, xc, (float*)d_out);
}

// Round 21
// 84.493 us; speedup vs baseline: 1.0380x; 1.0380x over previous
//
#include <hip/hip_runtime.h>
#include <hip/hip_bf16.h>

typedef __hip_bfloat16 bf16;

// ---------- constants ----------
// B=2, N=2048, C=128, H=8, hd=16, branches=3, hid=768
// rows per branch = B*N = 4096; 3C = 384
// I/O fp32; intermediates bf16 except xc (fp32 residual). Weights pre-transposed
// to bf16 Wt[N][K] (fused into k_pre). Q pre-scaled by 0.25*log2e (exp2-domain).
// V stored as tiled V^T: [bh][kb=key/64][d=16][key%64]. Attention: barrier-free,
// LDS-free, split-K (2x1024), two Q-tiles per wave with SHARED negm/m (merged
// guarded rescale, exact pow2), launch_bounds(128,3).
// qkv/fc1 GEMMs 64x128 tiles; proj/fc2 64x64. Split-K merge fused into k_proj_m.
// == R18 build (best measured: 84.47 us, absmax 0.03125). LN-fusion variant (R20)
// regressed (+3 us: col-slabs re-read fp32 A rows) and was reverted.

static __device__ __forceinline__ float b2f(bf16 h) { return __bfloat162float(h); }
static __device__ __forceinline__ bf16 f2b(float f) { return __float2bfloat16(f); }
static __device__ __forceinline__ unsigned short f2bu(float f) {
    bf16 h = f2b(f);
    return *reinterpret_cast<unsigned short*>(&h);
}
static __device__ __forceinline__ float bs2f(short s) {
    return __uint_as_float(((unsigned)(unsigned short)s) << 16);
}

typedef __attribute__((ext_vector_type(8))) short short8;
typedef __attribute__((ext_vector_type(4))) short short4v;
typedef __attribute__((ext_vector_type(16))) float f32x16;
typedef __attribute__((ext_vector_type(2))) int int2v;

#define QSCALE 0.36067376022224085f  // 0.25 * log2(e)

// ================= K0: fused weight transpose+convert AND LN1 =================
__global__ __launch_bounds__(256) void k_pre(const float* __restrict__ x1, const float* __restrict__ x2,
                                             const float* __restrict__ x3, const float* __restrict__ g,
                                             const float* __restrict__ b, bf16* __restrict__ xn,
                                             const float* __restrict__ qkv_w, const float* __restrict__ proj_w,
                                             const float* __restrict__ fc1_w, const float* __restrict__ fc2_w,
                                             bf16* __restrict__ wtq, bf16* __restrict__ wtp,
                                             bf16* __restrict__ wt1, bf16* __restrict__ wt2) {
    if (blockIdx.x >= 3072) {
        int idx = (blockIdx.x - 3072) * 256 + threadIdx.x;   // < 786432
        if (idx < 147456) {
            int bq = idx / 49152, i2 = idx % 49152;
            int n = i2 >> 7, k = i2 & 127;
            wtq[idx] = f2b(qkv_w[bq * 49152 + k * 384 + n]);
        } else if (idx < 196608) {
            int j = idx - 147456;
            int bq = j / 16384, i2 = j % 16384;
            int n = i2 >> 7, k = i2 & 127;
            wtp[j] = f2b(proj_w[bq * 16384 + k * 128 + n]);
        } else if (idx < 491520) {
            int j = idx - 196608;
            int n = j / 384, k = j - n * 384;
            wt1[j] = f2b(fc1_w[k * 768 + n]);
        } else {
            int j = idx - 491520;
            int n = j / 768, k = j - n * 768;
            wt2[j] = f2b(fc2_w[k * 384 + n]);
        }
        return;
    }
    int tid = threadIdx.x;
    int wave = tid >> 6, lane = tid & 63;
    int grow = blockIdx.x * 4 + wave;      // 0..12287
    int branch = grow >> 12;
    const float* xp = (branch == 0) ? x1 : (branch == 1 ? x2 : x3);
    const float* row = xp + (size_t)(grow & 4095) * 128;
    float2 a = *reinterpret_cast<const float2*>(&row[2 * lane]);
    float s = a.x + a.y, sq = a.x * a.x + a.y * a.y;
#pragma unroll
    for (int off = 32; off >= 1; off >>= 1) { s += __shfl_xor(s, off); sq += __shfl_xor(sq, off); }
    float mean = s * (1.f / 128.f);
    float var = sq * (1.f / 128.f) - mean * mean;
    float rstd = rsqrtf(var + 1e-5f);
    float2 gv = *reinterpret_cast<const float2*>(&g[branch * 128 + 2 * lane]);
    float2 bv = *reinterpret_cast<const float2*>(&b[branch * 128 + 2 * lane]);
    bf16* orow = xn + (size_t)grow * 128;
    orow[2 * lane] = f2b((a.x - mean) * rstd * gv.x + bv.x);
    orow[2 * lane + 1] = f2b((a.y - mean) * rstd * gv.y + bv.y);
}

// ================= shared MFMA GEMM tile: C64x64 = A[M,K] . Wt[N,K]^T =================
__device__ __forceinline__ f32x16 gemm_tile(const short* __restrict__ A, const short* __restrict__ W,
                                            int K, int rowbase, int colbase,
                                            short* als, short* wls) {
    int tid = threadIdx.x;
    int wid = tid >> 6, lane = tid & 63;
    int hi = lane >> 5, l31 = lane & 31;
    int wm = wid >> 1, wn = wid & 1;
    int sr = tid >> 3, skb = tid & 7;   // staging: row (0..31), k-block (0..7)
    f32x16 acc;
#pragma unroll
    for (int i = 0; i < 16; ++i) acc[i] = 0.f;
    for (int k0 = 0; k0 < K; k0 += 64) {
        __syncthreads();
#pragma unroll
        for (int pass = 0; pass < 2; ++pass) {
            int r = sr + pass * 32;
            short8 av = *(const short8*)&A[(size_t)(rowbase + r) * K + k0 + skb * 8];
            *(short8*)&als[r * 64 + ((skb ^ (r & 7)) * 8)] = av;
            short8 wv = *(const short8*)&W[(size_t)(colbase + r) * K + k0 + skb * 8];
            *(short8*)&wls[r * 64 + ((skb ^ (r & 7)) * 8)] = wv;
        }
        __syncthreads();
#pragma unroll
        for (int ks = 0; ks < 4; ++ks) {
            int ra = wm * 32 + l31;
            int rb = wn * 32 + l31;
            int kb = ks * 2 + hi;
            short8 af = *(const short8*)&als[ra * 64 + ((kb ^ (ra & 7)) * 8)];
            short8 bf = *(const short8*)&wls[rb * 64 + ((kb ^ (rb & 7)) * 8)];
            acc = __builtin_amdgcn_mfma_f32_32x32x16_bf16(af, bf, acc, 0, 0, 0);
        }
    }
    return acc;
}

// ================= wide MFMA GEMM tile: C64x128 = A[M,K] . Wt[N,K]^T (2 accs) =================
__device__ __forceinline__ void gemm_tile2(const short* __restrict__ A, const short* __restrict__ W,
                                           int K, int rowbase, int colbase,
                                           short* als, short* wls, f32x16& acc0, f32x16& acc1) {
    int tid = threadIdx.x;
    int wid = tid >> 6, lane = tid & 63;
    int hi = lane >> 5, l31 = lane & 31;
    int wm = wid >> 1, wn = wid & 1;
    int sr = tid >> 3, skb = tid & 7;
#pragma unroll
    for (int i = 0; i < 16; ++i) { acc0[i] = 0.f; acc1[i] = 0.f; }
    for (int k0 = 0; k0 < K; k0 += 64) {
        __syncthreads();
#pragma unroll
        for (int pass = 0; pass < 2; ++pass) {
            int r = sr + pass * 32;
            short8 av = *(const short8*)&A[(size_t)(rowbase + r) * K + k0 + skb * 8];
            *(short8*)&als[r * 64 + ((skb ^ (r & 7)) * 8)] = av;
        }
#pragma unroll
        for (int pass = 0; pass < 4; ++pass) {
            int r = sr + pass * 32;   // 0..127 (W rows = output cols)
            short8 wv = *(const short8*)&W[(size_t)(colbase + r) * K + k0 + skb * 8];
            *(short8*)&wls[r * 64 + ((skb ^ (r & 7)) * 8)] = wv;
        }
        __syncthreads();
#pragma unroll
        for (int ks = 0; ks < 4; ++ks) {
            int ra = wm * 32 + l31;
            int rb0 = wn * 64 + l31;
            int rb1 = wn * 64 + 32 + l31;
            int kb = ks * 2 + hi;
            short8 af = *(const short8*)&als[ra * 64 + ((kb ^ (ra & 7)) * 8)];
            short8 bf0 = *(const short8*)&wls[rb0 * 64 + ((kb ^ (rb0 & 7)) * 8)];
            short8 bf1 = *(const short8*)&wls[rb1 * 64 + ((kb ^ (rb1 & 7)) * 8)];
            acc0 = __builtin_amdgcn_mfma_f32_32x32x16_bf16(af, bf0, acc0, 0, 0, 0);
            acc1 = __builtin_amdgcn_mfma_f32_32x32x16_bf16(af, bf1, acc1, 0, 0, 0);
        }
    }
}

// ================= K2: QKV GEMM (64x128 tile); Q pre-scaled; V tiled-transposed =================
__global__ __launch_bounds__(256) void k_qkv_m(const bf16* __restrict__ xn, const bf16* __restrict__ wt,
                                               bf16* __restrict__ q, bf16* __restrict__ k, bf16* __restrict__ v) {
    __shared__ short als[64 * 64];     // 8 KB
    __shared__ short wls[128 * 64];    // 16 KB
    int branch = blockIdx.z;
    const short* A = (const short*)xn + (size_t)branch * 4096 * 128;
    const short* W = (const short*)wt + (size_t)branch * 384 * 128;
    int rowbase = blockIdx.x * 64, colbase = blockIdx.y * 128;
    f32x16 acc0, acc1;
    gemm_tile2(A, W, 128, rowbase, colbase, als, wls, acc0, acc1);
    int tid = threadIdx.x, wid = tid >> 6, lane = tid & 63;
    int hi = lane >> 5, l31 = lane & 31;
    int wm = wid >> 1, wn = wid & 1;
    int which = blockIdx.y;                 // 0=q, 1=k, 2=v (block-uniform)
    int c0 = wn * 64 + l31;                 // 0..127 within slab
    int c1 = c0 + 32;
    if (which < 2) {
        bf16* dst = (which == 0) ? q : k;
        float scl = (which == 0) ? QSCALE : 1.0f;
        int h0 = c0 >> 4, d0 = c0 & 15;
        int h1 = c1 >> 4, d1 = c1 & 15;
#pragma unroll
        for (int i = 0; i < 16; ++i) {
            int mrow = (i & 3) + 8 * (i >> 2) + 4 * hi;
            int token = rowbase + wm * 32 + mrow;
            int bb = token >> 11, n = token & 2047;
            size_t rowb = (((size_t)branch * 2 + bb) * 8);
            dst[((rowb + h0) * 2048 + n) * 16 + d0] = f2b(acc0[i] * scl);
            dst[((rowb + h1) * 2048 + n) * 16 + d1] = f2b(acc1[i] * scl);
        }
    } else {
        int h0 = c0 >> 4, d0 = c0 & 15;
        int h1 = c1 >> 4, d1 = c1 & 15;
#pragma unroll
        for (int i = 0; i < 16; ++i) {
            int mrow = (i & 3) + 8 * (i >> 2) + 4 * hi;
            int token = rowbase + wm * 32 + mrow;
            int bb = token >> 11, n = token & 2047;
            size_t bhb = ((size_t)(branch * 2 + bb) * 8);
            v[(((bhb + h0) * 32 + (n >> 6)) * 16 + d0) * 64 + (n & 63)] = f2b(acc0[i]);
            v[(((bhb + h1) * 32 + (n >> 6)) * 16 + d1) * 64 + (n & 63)] = f2b(acc1[i]);
        }
    }
}

// ---- one attention stream: QK (C=-m) -> exp2 -> cvt_pk -> permlane -> 4 PV into acc ----
static __device__ __forceinline__ void attn_stream(short8 kf0, short8 kf1,
                                                   short8 vf1, short8 vf2, short8 vf3, short8 vf4,
                                                   short8 qf, const f32x16& negm, f32x16& acc) {
    f32x16 pa = __builtin_amdgcn_mfma_f32_32x32x16_bf16(kf0, qf, negm, 0, 0, 0);
    f32x16 pb = __builtin_amdgcn_mfma_f32_32x32x16_bf16(kf1, qf, negm, 0, 0, 0);
#pragma unroll
    for (int r = 0; r < 16; ++r) pa[r] = __builtin_amdgcn_exp2f(pa[r]);
#pragma unroll
    for (int r = 0; r < 16; ++r) pb[r] = __builtin_amdgcn_exp2f(pb[r]);
    unsigned wa[8], wb[8];
#pragma unroll
    for (int e = 0; e < 8; ++e) {
        unsigned t;
        asm("v_cvt_pk_bf16_f32 %0, %1, %2" : "=v"(t) : "v"(pa[2 * e]), "v"(pa[2 * e + 1]));
        wa[e] = t;
        asm("v_cvt_pk_bf16_f32 %0, %1, %2" : "=v"(t) : "v"(pb[2 * e]), "v"(pb[2 * e + 1]));
        wb[e] = t;
    }
    union { unsigned u[4]; short8 v; } b1, b2, b3, b4;
    {
        auto r0 = __builtin_amdgcn_permlane32_swap((int)wa[0], (int)wa[2], false, false);
        b1.u[0] = (unsigned)r0[0]; b1.u[2] = (unsigned)r0[1];
        auto r1 = __builtin_amdgcn_permlane32_swap((int)wa[1], (int)wa[3], false, false);
        b1.u[1] = (unsigned)r1[0]; b1.u[3] = (unsigned)r1[1];
        auto r2 = __builtin_amdgcn_permlane32_swap((int)wa[4], (int)wa[6], false, false);
        b2.u[0] = (unsigned)r2[0]; b2.u[2] = (unsigned)r2[1];
        auto r3 = __builtin_amdgcn_permlane32_swap((int)wa[5], (int)wa[7], false, false);
        b2.u[1] = (unsigned)r3[0]; b2.u[3] = (unsigned)r3[1];
        auto r4 = __builtin_amdgcn_permlane32_swap((int)wb[0], (int)wb[2], false, false);
        b3.u[0] = (unsigned)r4[0]; b3.u[2] = (unsigned)r4[1];
        auto r5 = __builtin_amdgcn_permlane32_swap((int)wb[1], (int)wb[3], false, false);
        b3.u[1] = (unsigned)r5[0]; b3.u[3] = (unsigned)r5[1];
        auto r6 = __builtin_amdgcn_permlane32_swap((int)wb[4], (int)wb[6], false, false);
        b4.u[0] = (unsigned)r6[0]; b4.u[2] = (unsigned)r6[1];
        auto r7 = __builtin_amdgcn_permlane32_swap((int)wb[5], (int)wb[7], false, false);
        b4.u[1] = (unsigned)r7[0]; b4.u[3] = (unsigned)r7[1];
    }
    acc = __builtin_amdgcn_mfma_f32_32x32x16_bf16(vf1, b1.v, acc, 0, 0, 0);
    acc = __builtin_amdgcn_mfma_f32_32x32x16_bf16(vf2, b2.v, acc, 0, 0, 0);
    acc = __builtin_amdgcn_mfma_f32_32x32x16_bf16(vf3, b3.v, acc, 0, 0, 0);
    acc = __builtin_amdgcn_mfma_f32_32x32x16_bf16(vf4, b4.v, acc, 0, 0, 0);
}

// ================= K3: MFMA attention — 2 Q-tiles per wave, SHARED negm/m =================
// grid (48 bh, 16, 2 split), 128 threads = 2 waves; launch_bounds(128,3).
// Merged guarded rescale: if either stream's acc[8] exceeds 2^28, BOTH accs are scaled
// by the same 2^-shift (exact pow2). Loop-carried guard reads preserved (R11/R12).
__global__ __launch_bounds__(128, 3) void k_attn(const bf16* __restrict__ qg, const bf16* __restrict__ kg,
                                                 const bf16* __restrict__ vg, bf16* __restrict__ pacc,
                                                 float2* __restrict__ psm) {
    int bh = blockIdx.x;            // (branch*2+b)*8+h
    int qblk = blockIdx.y;          // 0..15 (tile B = qblk+16)
    int split = blockIdx.z;         // 0..1
    size_t base = (size_t)bh * (2048 * 16);
    size_t vtbase = (size_t)bh * 32768;   // tiled V^T base (32 tiles x 1024)
    int tid = threadIdx.x, wave = tid >> 6, lane = tid & 63;
    int hi = lane >> 5, l31 = lane & 31;
    int qrowA = qblk * 64 + wave * 32 + l31;
    int qrowB = (qblk + 16) * 64 + wave * 32 + l31;
    const short* qs = (const short*)qg;
    const short* ks = (const short*)kg;
    const short* vts = (const short*)vg;
    short8 qfA = *(const short8*)&qs[base + (size_t)qrowA * 16 + hi * 8];
    short8 qfB = *(const short8*)&qs[base + (size_t)qrowB * 16 + hi * 8];

    short8 one8;
#pragma unroll
    for (int j = 0; j < 8; ++j) one8[j] = (short)0x3F80;   // bf16 1.0

    f32x16 accA, accB, negm;
#pragma unroll
    for (int r = 0; r < 16; ++r) { accA[r] = 0.f; accB[r] = 0.f; negm[r] = -16.f; }
    float m = 16.f;

    int kbeg = split * 1024, kend = kbeg + 1024;

    for (int c0 = kbeg; c0 < kend; c0 += 64) {
        // merged guarded rescale (loop-carried reads of BOTH acc[8]); exact pow2 scale
        float mx = fmaxf(accA[8], accB[8]);
        if (__any(mx > 2.68435456e8f)) {   // 2^28
            int e = (__float_as_int(mx) >> 23) - 127;
            int shift = e > 16 ? e - 16 : 0;
            float fac = __int_as_float((127 - shift) << 23);   // 2^-shift
            m += (float)shift;
#pragma unroll
            for (int r = 0; r < 16; ++r) negm[r] = -m;
#pragma unroll
            for (int r = 0; r < 16; ++r) { accA[r] *= fac; accB[r] *= fac; }
        }
        short8 kf0 = *(const short8*)&ks[base + (size_t)(c0 + l31) * 16 + hi * 8];
        short8 kf1 = *(const short8*)&ks[base + (size_t)(c0 + 32 + l31) * 16 + hi * 8];
        short8 vf1 = one8, vf2 = one8, vf3 = one8, vf4 = one8;
        if (l31 < 16) {
            const short* vt = &vts[vtbase + (size_t)(c0 >> 6) * 1024 + l31 * 64 + hi * 8];
            vf1 = *(const short8*)&vt[0];
            vf2 = *(const short8*)&vt[16];
            vf3 = *(const short8*)&vt[32];
            vf4 = *(const short8*)&vt[48];
        }
        attn_stream(kf0, kf1, vf1, vf2, vf3, vf4, qfA, negm, accA);
        attn_stream(kf0, kf1, vf1, vf2, vf3, vf4, qfB, negm, accB);
    }
    short* pp = (short*)pacc;
    {
        size_t pidx = ((size_t)(split * 48 + bh) * 2048 + qrowA) * 16;
        unsigned u0 = (unsigned)f2bu(accA[0]) | ((unsigned)f2bu(accA[1]) << 16);
        unsigned u1 = (unsigned)f2bu(accA[2]) | ((unsigned)f2bu(accA[3]) << 16);
        unsigned u2 = (unsigned)f2bu(accA[4]) | ((unsigned)f2bu(accA[5]) << 16);
        unsigned u3 = (unsigned)f2bu(accA[6]) | ((unsigned)f2bu(accA[7]) << 16);
        int2v w01; w01.x = (int)u0; w01.y = (int)u1;
        int2v w23; w23.x = (int)u2; w23.y = (int)u3;
        *(int2v*)&pp[pidx + 4 * hi] = w01;
        *(int2v*)&pp[pidx + 8 + 4 * hi] = w23;
        if (hi == 0) {
            float2 sm; sm.x = accA[8]; sm.y = m;
            psm[(size_t)(split * 48 + bh) * 2048 + qrowA] = sm;
        }
    }
    {
        size_t pidx = ((size_t)(split * 48 + bh) * 2048 + qrowB) * 16;
        unsigned u0 = (unsigned)f2bu(accB[0]) | ((unsigned)f2bu(accB[1]) << 16);
        unsigned u1 = (unsigned)f2bu(accB[2]) | ((unsigned)f2bu(accB[3]) << 16);
        unsigned u2 = (unsigned)f2bu(accB[4]) | ((unsigned)f2bu(accB[5]) << 16);
        unsigned u3 = (unsigned)f2bu(accB[6]) | ((unsigned)f2bu(accB[7]) << 16);
        int2v w01; w01.x = (int)u0; w01.y = (int)u1;
        int2v w23; w23.x = (int)u2; w23.y = (int)u3;
        *(int2v*)&pp[pidx + 4 * hi] = w01;
        *(int2v*)&pp[pidx + 8 + 4 * hi] = w23;
        if (hi == 0) {
            float2 sm; sm.x = accB[8]; sm.y = m;
            psm[(size_t)(split * 48 + bh) * 2048 + qrowB] = sm;
        }
    }
}

// ================= K4: proj GEMM with FUSED split-K merge in A-staging =================
__global__ __launch_bounds__(256) void k_proj_m(const bf16* __restrict__ pacc, const float2* __restrict__ psm,
                                                const bf16* __restrict__ wt, const float* __restrict__ pb,
                                                const float* __restrict__ x1, const float* __restrict__ x2,
                                                const float* __restrict__ x3, float* __restrict__ xc) {
    __shared__ short als[64 * 64];
    __shared__ short wls[64 * 64];
    int branch = blockIdx.z;
    const short* W = (const short*)wt + (size_t)branch * 128 * 128;
    const short* pp = (const short*)pacc;
    int rowbase = blockIdx.x * 64, colbase = blockIdx.y * 64;
    int tid = threadIdx.x;
    int wid = tid >> 6, lane = tid & 63;
    int hi = lane >> 5, l31 = lane & 31;
    int wm = wid >> 1, wn = wid & 1;
    int sr = tid >> 3, skb = tid & 7;
    f32x16 acc;
#pragma unroll
    for (int i = 0; i < 16; ++i) acc[i] = 0.f;
    for (int k0 = 0; k0 < 128; k0 += 64) {
        __syncthreads();
#pragma unroll
        for (int pass = 0; pass < 2; ++pass) {
            int r = sr + pass * 32;
            int row = rowbase + r;                  // token row within branch
            int bb = row >> 11, n = row & 2047;
            int h = (k0 >> 4) + (skb >> 1);         // head for these 8 cols
            int dlo = (skb & 1) * 8;                // d offset (0 or 8)
            size_t bh = (size_t)(branch * 2 + bb) * 8 + h;
            size_t ridx = bh * 2048 + n;
            float2 sm0 = psm[ridx];
            float2 sm1 = psm[(size_t)48 * 2048 + ridx];
            float mp = fmaxf(sm0.y, sm1.y);
            float w0 = __builtin_amdgcn_exp2f(sm0.y - mp);
            float w1 = __builtin_amdgcn_exp2f(sm1.y - mp);
            float inv = 1.f / (sm0.x * w0 + sm1.x * w1);
            w0 *= inv; w1 *= inv;
            short8 a0 = *(const short8*)&pp[ridx * 16 + dlo];
            short8 a1 = *(const short8*)&pp[((size_t)48 * 2048 + ridx) * 16 + dlo];
            short8 av;
#pragma unroll
            for (int j = 0; j < 8; ++j)
                av[j] = (short)f2bu(bs2f(a0[j]) * w0 + bs2f(a1[j]) * w1);
            *(short8*)&als[r * 64 + ((skb ^ (r & 7)) * 8)] = av;
            short8 wv = *(const short8*)&W[(size_t)(colbase + r) * 128 + k0 + skb * 8];
            *(short8*)&wls[r * 64 + ((skb ^ (r & 7)) * 8)] = wv;
        }
        __syncthreads();
#pragma unroll
        for (int ks = 0; ks < 4; ++ks) {
            int ra = wm * 32 + l31;
            int rb = wn * 32 + l31;
            int kb = ks * 2 + hi;
            short8 af = *(const short8*)&als[ra * 64 + ((kb ^ (ra & 7)) * 8)];
            short8 bf = *(const short8*)&wls[rb * 64 + ((kb ^ (rb & 7)) * 8)];
            acc = __builtin_amdgcn_mfma_f32_32x32x16_bf16(af, bf, acc, 0, 0, 0);
        }
    }
    int c = colbase + wn * 32 + l31;        // 0..127
    float bias = pb[branch * 128 + c];
    const float* xp = (branch == 0) ? x1 : (branch == 1 ? x2 : x3);
#pragma unroll
    for (int i = 0; i < 16; ++i) {
        int mrow = (i & 3) + 8 * (i >> 2) + 4 * hi;
        int row = rowbase + wm * 32 + mrow;
        xc[(size_t)row * 384 + branch * 128 + c] = acc[i] + bias + xp[(size_t)row * 128 + c];
    }
}

// ================= K5: LN2 over 384 features =================
__global__ __launch_bounds__(256) void k_ln2(const float* __restrict__ xc, const float* __restrict__ g,
                                             const float* __restrict__ b, bf16* __restrict__ xcn) {
    int tid = threadIdx.x, wave = tid >> 6, lane = tid & 63;
    int row = blockIdx.x * 4 + wave;  // 0..4095
    const float* rp = xc + (size_t)row * 384;
    float v[6];
    float s = 0.f, sq = 0.f;
#pragma unroll
    for (int i = 0; i < 6; ++i) {
        v[i] = rp[lane + i * 64];
        s += v[i]; sq += v[i] * v[i];
    }
#pragma unroll
    for (int off = 32; off >= 1; off >>= 1) { s += __shfl_xor(s, off); sq += __shfl_xor(sq, off); }
    float mean = s * (1.f / 384.f);
    float var = sq * (1.f / 384.f) - mean * mean;
    float rstd = rsqrtf(var + 1e-5f);
    bf16* op = xcn + (size_t)row * 384;
#pragma unroll
    for (int i = 0; i < 6; ++i) {
        int c = lane + i * 64;
        op[c] = f2b((v[i] - mean) * rstd * g[c] + b[c]);
    }
}

// ================= K6: FC1 GEMM (64x128 tile) + bias + exact GELU -> h bf16 =================
__global__ __launch_bounds__(256) void k_fc1_m(const bf16* __restrict__ xcn, const bf16* __restrict__ wt,
                                               const float* __restrict__ bias, bf16* __restrict__ h) {
    __shared__ short als[64 * 64];     // 8 KB
    __shared__ short wls[128 * 64];    // 16 KB
    const short* A = (const short*)xcn;
    const short* W = (const short*)wt;
    int rowbase = blockIdx.x * 64, colbase = blockIdx.y * 128;
    f32x16 acc0, acc1;
    gemm_tile2(A, W, 384, rowbase, colbase, als, wls, acc0, acc1);
    int tid = threadIdx.x, wid = tid >> 6, lane = tid & 63;
    int hi = lane >> 5, l31 = lane & 31;
    int wm = wid >> 1, wn = wid & 1;
    int c0 = colbase + wn * 64 + l31;       // 0..767
    int c1 = c0 + 32;
    float bs0 = bias[c0];
    float bs1 = bias[c1];
#pragma unroll
    for (int i = 0; i < 16; ++i) {
        int mrow = (i & 3) + 8 * (i >> 2) + 4 * hi;
        int row = rowbase + wm * 32 + mrow;
        float v0 = acc0[i] + bs0;
        float v1 = acc1[i] + bs1;
        float g0 = 0.5f * v0 * (1.f + erff(v0 * 0.70710678118f));
        float g1 = 0.5f * v1 * (1.f + erff(v1 * 0.70710678118f));
        h[(size_t)row * 768 + c0] = f2b(g0);
        h[(size_t)row * 768 + c1] = f2b(g1);
    }
}

// ================= K7: FC2 GEMM (MFMA) + bias + residual -> split fp32 outputs =================
__global__ __launch_bounds__(256) void k_fc2_m(const bf16* __restrict__ h, const bf16* __restrict__ wt,
                                               const float* __restrict__ bias, const float* __restrict__ xc,
                                               float* __restrict__ outp) {
    __shared__ short als[64 * 64];
    __shared__ short wls[64 * 64];
    const short* A = (const short*)h;
    const short* W = (const short*)wt;
    int rowbase = blockIdx.x * 64, colbase = blockIdx.y * 64;
    f32x16 acc = gemm_tile(A, W, 768, rowbase, colbase, als, wls);
    int tid = threadIdx.x, wid = tid >> 6, lane = tid & 63;
    int hi = lane >> 5, l31 = lane & 31;
    int wm = wid >> 1, wn = wid & 1;
    int c = colbase + wn * 32 + l31;        // 0..383
    float bs = bias[c];
    int which = c >> 7, cc = c & 127;
#pragma unroll
    for (int i = 0; i < 16; ++i) {
        int mrow = (i & 3) + 8 * (i >> 2) + 4 * hi;
        int row = rowbase + wm * 32 + mrow;
        outp[(size_t)which * 524288 + (size_t)row * 128 + cc] = acc[i] + bs + xc[(size_t)row * 384 + c];
    }
}

// ================= launch =================
extern "C" void kernel_launch(void* const* d_in, const int* in_sizes, int n_in,
                              void* d_out, int out_size, void* d_ws, size_t ws_size,
                              hipStream_t stream) {
    const float* x1     = (const float*)d_in[0];
    const float* x2     = (const float*)d_in[1];
    const float* x3     = (const float*)d_in[2];
    const float* ln1_g  = (const float*)d_in[3];
    const float* ln1_b  = (const float*)d_in[4];
    const float* qkv_w  = (const float*)d_in[5];
    const float* proj_w = (const float*)d_in[6];
    const float* proj_b = (const float*)d_in[7];
    const float* ln2_g  = (const float*)d_in[8];
    const float* ln2_b  = (const float*)d_in[9];
    const float* fc1_w  = (const float*)d_in[10];
    const float* fc1_b  = (const float*)d_in[11];
    const float* fc2_w  = (const float*)d_in[12];
    const float* fc2_b  = (const float*)d_in[13];

    char* ws = (char*)d_ws;
    const size_t SB = 3145728;  // bf16 buffer of 1.5M elems
    bf16* xn  = (bf16*)(ws + 0 * SB);
    bf16* qb  = (bf16*)(ws + 1 * SB);
    bf16* kb  = (bf16*)(ws + 2 * SB);
    bf16* vb  = (bf16*)(ws + 3 * SB);   // tiled V^T
    float* xc = (float*)(ws + 5 * SB);            // 4096*384*4 = 6291456 B
    bf16* xcn = (bf16*)(ws + 5 * SB + 6291456);   // 3145728 B
    bf16* hb  = (bf16*)(ws + 6 * SB + 6291456);   // 4096*768*2 = 6291456 B
    char* wbase = ws + 31457280;
    bf16* wtq = (bf16*)(wbase);                   // 3*384*128*2 = 294912
    bf16* wtp = (bf16*)(wbase + 294912);          // 3*128*128*2 = 98304
    bf16* wt1 = (bf16*)(wbase + 393216);          // 768*384*2   = 589824
    bf16* wt2 = (bf16*)(wbase + 983040);          // 384*768*2   = 589824
    // total = 33030144 B (~31.5 MB)
    // Split-K attention partials OVERLAY xcn+hb (both written only after proj reads them):
    bf16*  pacc = (bf16*)(ws + 22020096);         // 2*48*2048*16*2 = 6291456 B
    float2* psm = (float2*)(ws + 28311552);       // 2*48*2048*8    = 1572864 B

    k_pre<<<6144, 256, 0, stream>>>(x1, x2, x3, ln1_g, ln1_b, xn,
                                    qkv_w, proj_w, fc1_w, fc2_w, wtq, wtp, wt1, wt2);
    k_qkv_m<<<dim3(64, 3, 3), 256, 0, stream>>>(xn, wtq, qb, kb, vb);
    k_attn<<<dim3(48, 16, 2), 128, 0, stream>>>(qb, kb, vb, pacc, psm);
    k_proj_m<<<dim3(64, 2, 3), 256, 0, stream>>>(pacc, psm, wtp, proj_b, x1, x2, x3, xc);
    k_ln2<<<1024, 256, 0, stream>>>(xc, ln2_g, ln2_b, xcn);
    k_fc1_m<<<dim3(64, 6, 1), 256, 0, stream>>>(xcn, wt1, fc1_b, hb);
    k_fc2_m<<<dim3(64, 6, 1), 256, 0, stream>>>(hb, wt2, fc2_b, xc, (float*)d_out);
}